// Round 1
// baseline (227.840 us; speedup 1.0000x reference)
//
#include <hip/hip_runtime.h>

#define NB 4
#define NC_USED 9            // classes 1..9 (background ignored, class 0 never needed)
#define BATCH_ELEMS (160*160*160)   // 4,096,000
#define BLOCKS_PER_BATCH 256
#define THREADS 256

// d_ws layout: uint32 cnt[NB][3][NC_USED]  (0=pred count, 1=true count, 2=intersection)

__global__ __launch_bounds__(THREADS) void dice_hist_kernel(
    const int* __restrict__ y_pred,
    const int* __restrict__ y_true,
    unsigned int* __restrict__ cnt)
{
    const int batch    = blockIdx.x / BLOCKS_PER_BATCH;
    const int bInBatch = blockIdx.x % BLOCKS_PER_BATCH;

    const int4* __restrict__ p = (const int4*)(y_pred + (size_t)batch * BATCH_ELEMS);
    const int4* __restrict__ t = (const int4*)(y_true + (size_t)batch * BATCH_ELEMS);
    const int nvec = BATCH_ELEMS / 4;            // 1,024,000 int4 per batch

    unsigned int predc[NC_USED];
    unsigned int truec[NC_USED];
    unsigned int interc[NC_USED];
    #pragma unroll
    for (int c = 0; c < NC_USED; ++c) { predc[c] = 0; truec[c] = 0; interc[c] = 0; }

    const int stride = BLOCKS_PER_BATCH * THREADS;
    for (int i = bInBatch * THREADS + threadIdx.x; i < nvec; i += stride) {
        int4 a = p[i];
        int4 b = t[i];
        int ap[4] = {a.x, a.y, a.z, a.w};
        int bp[4] = {b.x, b.y, b.z, b.w};
        #pragma unroll
        for (int j = 0; j < 4; ++j) {
            #pragma unroll
            for (int c = 1; c <= NC_USED; ++c) {
                unsigned int pa = (ap[j] == c) ? 1u : 0u;
                unsigned int pb = (bp[j] == c) ? 1u : 0u;
                predc[c-1]  += pa;
                truec[c-1]  += pb;
                interc[c-1] += pa & pb;
            }
        }
    }

    // Block reduction via LDS atomics (once per thread, 27 adds), then 27
    // global atomics per block.
    __shared__ unsigned int scnt[3 * NC_USED];
    if (threadIdx.x < 3 * NC_USED) scnt[threadIdx.x] = 0u;
    __syncthreads();
    #pragma unroll
    for (int c = 0; c < NC_USED; ++c) {
        atomicAdd(&scnt[0 * NC_USED + c], predc[c]);
        atomicAdd(&scnt[1 * NC_USED + c], truec[c]);
        atomicAdd(&scnt[2 * NC_USED + c], interc[c]);
    }
    __syncthreads();
    if (threadIdx.x < 3 * NC_USED) {
        atomicAdd(&cnt[batch * (3 * NC_USED) + threadIdx.x], scnt[threadIdx.x]);
    }
}

__global__ void dice_finish_kernel(const unsigned int* __restrict__ cnt,
                                   float* __restrict__ out)
{
    if (blockIdx.x == 0 && threadIdx.x == 0) {
        float loss = 0.0f;
        for (int n = 0; n < NB; ++n) {
            const unsigned int* c = cnt + n * (3 * NC_USED);
            float tsum = 0.0f;
            for (int i = 0; i < NC_USED; ++i) tsum += (float)c[1 * NC_USED + i];
            for (int i = 0; i < NC_USED; ++i) {
                float cp = (float)c[0 * NC_USED + i];
                float ct = (float)c[1 * NC_USED + i];
                float I  = (float)c[2 * NC_USED + i];
                float denom = cp + ct;
                if (denom > 0.0f) {
                    float w = ct / tsum / (float)NB;
                    loss += w * (2.0f * I / denom);
                }
            }
        }
        out[0] = 1.0f - loss;
    }
}

extern "C" void kernel_launch(void* const* d_in, const int* in_sizes, int n_in,
                              void* d_out, int out_size, void* d_ws, size_t ws_size,
                              hipStream_t stream) {
    const int* y_pred = (const int*)d_in[0];
    const int* y_true = (const int*)d_in[1];
    unsigned int* cnt = (unsigned int*)d_ws;

    // Zero the 4*3*9 = 108 counters (ws is re-poisoned to 0xAA before every launch).
    hipMemsetAsync(d_ws, 0, NB * 3 * NC_USED * sizeof(unsigned int), stream);

    dice_hist_kernel<<<NB * BLOCKS_PER_BATCH, THREADS, 0, stream>>>(y_pred, y_true, cnt);
    dice_finish_kernel<<<1, 64, 0, stream>>>(cnt, (float*)d_out);
}

// Round 2
// 158.996 us; speedup vs baseline: 1.4330x; 1.4330x over previous
//
#include <hip/hip_runtime.h>

#define NB 4
#define NC 9                        // classes 1..9 (background ignored)
#define BATCH_ELEMS (160*160*160)   // 4,096,000
#define NVEC (BATCH_ELEMS/4)        // 1,024,000 int4 per batch
#define BPB 500                     // blocks per batch
#define THREADS 256
#define TPB_BATCH (BPB*THREADS)     // 128,000 threads per batch
#define VEC_PER_THREAD (NVEC/TPB_BATCH)  // exactly 8 -> 32 elements/thread
#define NBLK (NB*BPB)               // 2000 blocks
#define NPACK 14                    // 27 counters packed as 16-bit pairs

// counter index k = type*9 + (class-1); type 0=pred,1=true,2=inter
// d_ws layout: u32 cnt[NBLK][NPACK], packed lo=k(2j), hi=k(2j+1)

__device__ __forceinline__ void proc(int a, int b,
                                     unsigned long long& accP,
                                     unsigned long long& accT,
                                     unsigned long long& accI)
{
    // 6-bit field per class value 0..9 (bits [6v, 6v+6)); per-thread max 32 < 63
    unsigned long long sa = 1ull << (6 * a);
    unsigned long long sb = 1ull << (6 * b);
    accP += sa;
    accT += sb;
    accI += (a == b) ? sa : 0ull;
}

__global__ __launch_bounds__(THREADS, 8) void dice_hist_kernel(
    const int* __restrict__ y_pred,
    const int* __restrict__ y_true,
    unsigned int* __restrict__ cnt)
{
    const int batch = blockIdx.x / BPB;
    const int bIn   = blockIdx.x % BPB;
    const int4* __restrict__ p = (const int4*)(y_pred + (size_t)batch * BATCH_ELEMS);
    const int4* __restrict__ t = (const int4*)(y_true + (size_t)batch * BATCH_ELEMS);
    const int tid = bIn * THREADS + threadIdx.x;   // 0..127,999

    unsigned long long accP = 0ull, accT = 0ull, accI = 0ull;

    #pragma unroll
    for (int k = 0; k < VEC_PER_THREAD; k += 2) {
        int4 a0 = p[tid + k * TPB_BATCH];
        int4 b0 = t[tid + k * TPB_BATCH];
        int4 a1 = p[tid + (k + 1) * TPB_BATCH];
        int4 b1 = t[tid + (k + 1) * TPB_BATCH];
        proc(a0.x, b0.x, accP, accT, accI);
        proc(a0.y, b0.y, accP, accT, accI);
        proc(a0.z, b0.z, accP, accT, accI);
        proc(a0.w, b0.w, accP, accT, accI);
        proc(a1.x, b1.x, accP, accT, accI);
        proc(a1.y, b1.y, accP, accT, accI);
        proc(a1.z, b1.z, accP, accT, accI);
        proc(a1.w, b1.w, accP, accT, accI);
    }

    // Extract 27 per-thread counts, packed two per u32 (16-bit halves).
    unsigned int packed[NPACK];
    #pragma unroll
    for (int j = 0; j < NPACK; ++j) {
        int k0 = 2 * j, k1 = 2 * j + 1;
        int c0 = (k0 % 9) + 1, t0 = k0 / 9;
        unsigned long long a0 = (t0 == 0) ? accP : (t0 == 1) ? accT : accI;
        unsigned int v0 = (unsigned int)((a0 >> (6 * c0)) & 63ull);
        unsigned int v1 = 0;
        if (k1 < 27) {
            int c1 = (k1 % 9) + 1, t1 = k1 / 9;
            unsigned long long a1 = (t1 == 0) ? accP : (t1 == 1) ? accT : accI;
            v1 = (unsigned int)((a1 >> (6 * c1)) & 63ull);
        }
        packed[j] = v0 | (v1 << 16);
    }

    // Wave reduction (64 lanes): 16-bit halves max 32*64=2048, no overflow.
    #pragma unroll
    for (int off = 32; off > 0; off >>= 1) {
        #pragma unroll
        for (int j = 0; j < NPACK; ++j)
            packed[j] += __shfl_down(packed[j], off, 64);
    }

    __shared__ unsigned int swave[4][NPACK];
    const int wave = threadIdx.x >> 6;
    const int lane = threadIdx.x & 63;
    if (lane == 0) {
        #pragma unroll
        for (int j = 0; j < NPACK; ++j) swave[wave][j] = packed[j];
    }
    __syncthreads();
    if (threadIdx.x < NPACK) {
        // per-block per-class max 256*32 = 8192, fits 16-bit halves
        unsigned int s = swave[0][threadIdx.x] + swave[1][threadIdx.x]
                       + swave[2][threadIdx.x] + swave[3][threadIdx.x];
        cnt[blockIdx.x * NPACK + threadIdx.x] = s;
    }
}

__global__ __launch_bounds__(256) void dice_finish_kernel(
    const unsigned int* __restrict__ cnt, float* __restrict__ out)
{
    __shared__ unsigned int tot[NB * 28];
    const int t = threadIdx.x;
    if (t < NB * 28) tot[t] = 0u;
    __syncthreads();

    if (t < 224) {                       // 4 batches * 14 pairs * 4 sub-chunks
        const int g     = t >> 2;        // 0..55 : (batch, pair)
        const int sub   = t & 3;
        const int batch = g / NPACK;
        const int j     = g % NPACK;
        unsigned int lo = 0, hi = 0;
        const int base = batch * BPB;
        const int b0 = sub * (BPB / 4), b1 = b0 + (BPB / 4);   // 125 each
        for (int b = b0; b < b1; ++b) {
            unsigned int v = cnt[(base + b) * NPACK + j];
            lo += v & 0xFFFFu;
            hi += v >> 16;
        }
        atomicAdd(&tot[batch * 28 + 2 * j], lo);
        atomicAdd(&tot[batch * 28 + 2 * j + 1], hi);
    }
    __syncthreads();

    if (t == 0) {
        float loss = 0.0f;
        for (int n = 0; n < NB; ++n) {
            const unsigned int* c = &tot[n * 28];
            float tsum = 0.0f;
            for (int i = 0; i < NC; ++i) tsum += (float)c[9 + i];
            for (int i = 0; i < NC; ++i) {
                float cp = (float)c[0 + i];
                float ct = (float)c[9 + i];
                float I  = (float)c[18 + i];
                float denom = cp + ct;
                if (denom > 0.0f)
                    loss += (ct / tsum / (float)NB) * (2.0f * I / denom);
            }
        }
        out[0] = 1.0f - loss;
    }
}

extern "C" void kernel_launch(void* const* d_in, const int* in_sizes, int n_in,
                              void* d_out, int out_size, void* d_ws, size_t ws_size,
                              hipStream_t stream) {
    const int* y_pred = (const int*)d_in[0];
    const int* y_true = (const int*)d_in[1];
    unsigned int* cnt = (unsigned int*)d_ws;   // NBLK*NPACK u32 = 112 KB, fully overwritten

    dice_hist_kernel<<<NBLK, THREADS, 0, stream>>>(y_pred, y_true, cnt);
    dice_finish_kernel<<<1, 256, 0, stream>>>(cnt, (float*)d_out);
}